// Round 1
// baseline (1014.032 us; speedup 1.0000x reference)
//
#include <hip/hip_runtime.h>

#define N_NODES 50000
#define N_EDGES 600000
#define F_IN    500
#define H_DIM   64
#define C_OUT   40
#define STEPS   4

// ---------------- Encoder: h = x @ m1_w + m1_b ; z = x0 = h ----------------
// block 256 = 4 groups of 64 lanes; each group handles 8 rows, lane = col.
__global__ __launch_bounds__(256) void encoder_kernel(
    const float* __restrict__ x, const float* __restrict__ W,
    const float* __restrict__ b, float* __restrict__ x0, float* __restrict__ z)
{
    int col = threadIdx.x & 63;
    int g   = threadIdx.x >> 6;            // 0..3
    int r0  = blockIdx.x * 32 + g * 8;     // 8 rows per thread
    if (r0 >= N_NODES) return;

    const float* xp[8];
    #pragma unroll
    for (int i = 0; i < 8; ++i) {
        int r = r0 + i;
        if (r > N_NODES - 1) r = N_NODES - 1;   // clamp (redundant loads, guarded store)
        xp[i] = x + (size_t)r * F_IN;
    }
    float acc[8];
    #pragma unroll
    for (int i = 0; i < 8; ++i) acc[i] = 0.f;

    for (int k = 0; k < F_IN; ++k) {
        float wv = W[k * H_DIM + col];
        #pragma unroll
        for (int i = 0; i < 8; ++i)
            acc[i] = fmaf(xp[i][k], wv, acc[i]);
    }
    float bias = b[col];
    #pragma unroll
    for (int i = 0; i < 8; ++i) {
        int r = r0 + i;
        if (r < N_NODES) {
            float v = acc[i] + bias;
            x0[r * H_DIM + col] = v;
            z [r * H_DIM + col] = v;
        }
    }
}

// ---------------- CSR build ----------------
__global__ void hist_kernel(const int* __restrict__ src, int* __restrict__ counts)
{
    int e = blockIdx.x * 256 + threadIdx.x;
    if (e < N_EDGES) atomicAdd(&counts[src[e]], 1);
}

__global__ __launch_bounds__(256) void scan_kernel(
    const int* __restrict__ counts, int* __restrict__ off, int* __restrict__ cursor)
{
    __shared__ int sums[256];
    __shared__ int bases[257];
    int tid = threadIdx.x;
    const int chunk = (N_NODES + 255) / 256;   // 196
    int s0 = tid * chunk;
    int s1 = s0 + chunk; if (s1 > N_NODES) s1 = N_NODES;
    int s = 0;
    for (int i = s0; i < s1; ++i) s += counts[i];
    sums[tid] = s;
    __syncthreads();
    if (tid == 0) {
        int r = 0;
        for (int i = 0; i < 256; ++i) { bases[i] = r; r += sums[i]; }
        bases[256] = r;
    }
    __syncthreads();
    int r = bases[tid];
    for (int i = s0; i < s1; ++i) {
        off[i] = r; cursor[i] = r; r += counts[i];
    }
    if (tid == 0) off[N_NODES] = bases[256];
}

__global__ void scatter_kernel(const int* __restrict__ src, const int* __restrict__ dst,
                               const float* __restrict__ w,
                               int* __restrict__ cursor, int* __restrict__ dsts,
                               float* __restrict__ wst)
{
    int e = blockIdx.x * 256 + threadIdx.x;
    if (e < N_EDGES) {
        int s = src[e];
        int p = atomicAdd(&cursor[s], 1);
        dsts[p] = dst[e];
        wst[p]  = w[e];
    }
}

// ---------------- Fused RK4 stage: az = A zs ; k = a*(az - zs) + x0 -------
// stage 0: acc  = k;      out = z + cnext*k      (cnext = dt/2)
// stage 1: acc += 2k;     out = z + cnext*k      (cnext = dt/2)
// stage 2: acc += 2k;     out = z + cnext*k      (cnext = dt)
// stage 3:                out = z + cnext*(acc+k) (cnext = dt/6) -> writes z
// 16 threads per node, each owns a float4 of the 64 columns.
__global__ __launch_bounds__(256) void stage_kernel(
    const int* __restrict__ off, const int* __restrict__ dsts,
    const float* __restrict__ wst,
    const float* __restrict__ zs, const float* zbase,
    const float* __restrict__ x0, const float* __restrict__ alpha,
    float* __restrict__ acc, float* out,
    int stage, float cnext)
{
    int node = blockIdx.x * 16 + (threadIdx.x >> 4);
    if (node >= N_NODES) return;
    int c = (threadIdx.x & 15) << 2;

    int jb = off[node], je = off[node + 1];
    float4 az = make_float4(0.f, 0.f, 0.f, 0.f);
    for (int j = jb; j < je; ++j) {
        int   d = dsts[j];
        float w = wst[j];
        const float4 zv = *reinterpret_cast<const float4*>(zs + (size_t)d * H_DIM + c);
        az.x = fmaf(w, zv.x, az.x);
        az.y = fmaf(w, zv.y, az.y);
        az.z = fmaf(w, zv.z, az.z);
        az.w = fmaf(w, zv.w, az.w);
    }

    size_t idx = (size_t)node * H_DIM + c;
    const float4 zsv = *reinterpret_cast<const float4*>(zs + idx);
    const float4 x0v = *reinterpret_cast<const float4*>(x0 + idx);
    float a = 0.5f / (1.f + __expf(-alpha[node]));   // 0.5 * sigmoid(alpha)

    float4 k;
    k.x = fmaf(a, az.x - zsv.x, x0v.x);
    k.y = fmaf(a, az.y - zsv.y, x0v.y);
    k.z = fmaf(a, az.z - zsv.z, x0v.z);
    k.w = fmaf(a, az.w - zsv.w, x0v.w);

    float4 zb = *reinterpret_cast<const float4*>(zbase + idx);
    float4 o;
    if (stage == 3) {
        float4 av = *reinterpret_cast<const float4*>(acc + idx);
        o.x = fmaf(cnext, av.x + k.x, zb.x);
        o.y = fmaf(cnext, av.y + k.y, zb.y);
        o.z = fmaf(cnext, av.z + k.z, zb.z);
        o.w = fmaf(cnext, av.w + k.w, zb.w);
    } else {
        if (stage == 0) {
            *reinterpret_cast<float4*>(acc + idx) = k;
        } else {
            float4 av = *reinterpret_cast<const float4*>(acc + idx);
            av.x = fmaf(2.f, k.x, av.x);
            av.y = fmaf(2.f, k.y, av.y);
            av.z = fmaf(2.f, k.z, av.z);
            av.w = fmaf(2.f, k.w, av.w);
            *reinterpret_cast<float4*>(acc + idx) = av;
        }
        o.x = fmaf(cnext, k.x, zb.x);
        o.y = fmaf(cnext, k.y, zb.y);
        o.z = fmaf(cnext, k.z, zb.z);
        o.w = fmaf(cnext, k.w, zb.w);
    }
    *reinterpret_cast<float4*>(out + idx) = o;
}

// ---------------- Decoder: out = relu(z) @ m2_w + m2_b ----------------
__global__ __launch_bounds__(256) void decoder_kernel(
    const float* __restrict__ z, const float* __restrict__ W2,
    const float* __restrict__ b2, float* __restrict__ out)
{
    int node = blockIdx.x * 4 + (threadIdx.x >> 6);
    int cc   = threadIdx.x & 63;
    if (node >= N_NODES || cc >= C_OUT) return;
    const float* zr = z + (size_t)node * H_DIM;
    float acc = 0.f;
    for (int k = 0; k < H_DIM; ++k) {
        float zv = zr[k];
        zv = zv > 0.f ? zv : 0.f;
        acc = fmaf(zv, W2[k * C_OUT + cc], acc);
    }
    out[node * C_OUT + cc] = acc + b2[cc];
}

extern "C" void kernel_launch(void* const* d_in, const int* in_sizes, int n_in,
                              void* d_out, int out_size, void* d_ws, size_t ws_size,
                              hipStream_t stream)
{
    const float* x     = (const float*)d_in[0];
    const float* ew    = (const float*)d_in[1];
    const float* m1w   = (const float*)d_in[2];
    const float* m1b   = (const float*)d_in[3];
    const float* alpha = (const float*)d_in[4];
    const float* m2w   = (const float*)d_in[5];
    const float* m2b   = (const float*)d_in[6];
    const int*   esrc  = (const int*)d_in[7];
    const int*   edst  = (const int*)d_in[8];
    float* out = (float*)d_out;

    char* ws = (char*)d_ws;
    size_t o = 0;
    auto alloc = [&](size_t bytes) -> void* {
        void* p = ws + o;
        o = (o + bytes + 255) & ~(size_t)255;
        return p;
    };
    float* x0     = (float*)alloc((size_t)N_NODES * H_DIM * 4);
    float* z      = (float*)alloc((size_t)N_NODES * H_DIM * 4);
    float* ztA    = (float*)alloc((size_t)N_NODES * H_DIM * 4);
    float* ztB    = (float*)alloc((size_t)N_NODES * H_DIM * 4);
    float* acc    = (float*)alloc((size_t)N_NODES * H_DIM * 4);
    int*   counts = (int*)alloc((size_t)N_NODES * 4);
    int*   off    = (int*)alloc((size_t)(N_NODES + 1) * 4);
    int*   cursor = (int*)alloc((size_t)N_NODES * 4);
    int*   dsts   = (int*)alloc((size_t)N_EDGES * 4);
    float* wst    = (float*)alloc((size_t)N_EDGES * 4);

    // CSR build (deterministic up to fp-add order within a node's edge list)
    hipMemsetAsync(counts, 0, (size_t)N_NODES * 4, stream);
    hist_kernel<<<(N_EDGES + 255) / 256, 256, 0, stream>>>(esrc, counts);
    scan_kernel<<<1, 256, 0, stream>>>(counts, off, cursor);
    scatter_kernel<<<(N_EDGES + 255) / 256, 256, 0, stream>>>(esrc, edst, ew, cursor, dsts, wst);

    // Encoder
    encoder_kernel<<<(N_NODES + 31) / 32, 256, 0, stream>>>(x, m1w, m1b, x0, z);

    // RK4
    const float dt = 1.0f / STEPS;
    int sgrid = (N_NODES + 15) / 16;
    for (int step = 0; step < STEPS; ++step) {
        stage_kernel<<<sgrid, 256, 0, stream>>>(off, dsts, wst, z,   z, x0, alpha, acc, ztA, 0, 0.5f * dt);
        stage_kernel<<<sgrid, 256, 0, stream>>>(off, dsts, wst, ztA, z, x0, alpha, acc, ztB, 1, 0.5f * dt);
        stage_kernel<<<sgrid, 256, 0, stream>>>(off, dsts, wst, ztB, z, x0, alpha, acc, ztA, 2, dt);
        stage_kernel<<<sgrid, 256, 0, stream>>>(off, dsts, wst, ztA, z, x0, alpha, acc, z,   3, dt / 6.0f);
    }

    // Decoder
    decoder_kernel<<<(N_NODES + 3) / 4, 256, 0, stream>>>(z, m2w, m2b, out);
}

// Round 2
// 848.082 us; speedup vs baseline: 1.1957x; 1.1957x over previous
//
#include <hip/hip_runtime.h>

#define N_NODES 50000
#define N_EDGES 600000
#define F_IN    500
#define H_DIM   64
#define C_OUT   40
#define STEPS   4

// ---------------- Encoder: h = x @ m1_w + m1_b ; z = x0 = h ----------------
// Tiled GEMM: block = 256 threads computes BM=128 rows x 64 cols.
// X tile staged TRANSPOSED in LDS (xs[k][row]) so compute reads are vector b128.
#define BM 128
#define BK 32
#define XS_STRIDE (BM + 4)    // 132: write banks (4*(4f4+j)+row)%32 -> <=4-way
#define WS_STRIDE (H_DIM + 4) // 68

__global__ __launch_bounds__(256) void encoder_kernel(
    const float* __restrict__ x, const float* __restrict__ W,
    const float* __restrict__ b, float* __restrict__ x0, float* __restrict__ z)
{
    __shared__ __align__(16) float xs[BK][XS_STRIDE];
    __shared__ __align__(16) float ws[BK][WS_STRIDE];

    int t    = threadIdx.x;
    int r0   = blockIdx.x * BM;
    int trow = t >> 4;   // 0..15 -> rows trow*8 .. trow*8+7
    int tc   = t & 15;   // cols tc*4 .. tc*4+3

    float acc[8][4];
    #pragma unroll
    for (int i = 0; i < 8; ++i)
        #pragma unroll
        for (int j = 0; j < 4; ++j) acc[i][j] = 0.f;

    for (int k0 = 0; k0 < 512; k0 += BK) {
        // ---- stage X tile: 128 rows x 32 k = 1024 float4, 4 per thread ----
        #pragma unroll
        for (int s = 0; s < 4; ++s) {
            int idx = s * 256 + t;
            int row = idx >> 3;          // 0..127
            int f4  = idx & 7;           // 0..7 (16B chunk within the 32-k slab)
            int gr  = r0 + row; if (gr >= N_NODES) gr = N_NODES - 1;
            int gk  = k0 + f4 * 4;
            float4 v = make_float4(0.f, 0.f, 0.f, 0.f);
            if (gk + 3 < F_IN)          // F_IN%4==0 so all-or-nothing
                v = *reinterpret_cast<const float4*>(x + (size_t)gr * F_IN + gk);
            xs[f4 * 4 + 0][row] = v.x;
            xs[f4 * 4 + 1][row] = v.y;
            xs[f4 * 4 + 2][row] = v.z;
            xs[f4 * 4 + 3][row] = v.w;
        }
        // ---- stage W tile: 32 k x 64 cols = 512 float4, 2 per thread ----
        #pragma unroll
        for (int s = 0; s < 2; ++s) {
            int idx  = s * 256 + t;
            int krow = idx >> 4;         // 0..31
            int f4c  = idx & 15;         // 0..15
            int gk   = k0 + krow;
            float4 v = make_float4(0.f, 0.f, 0.f, 0.f);
            if (gk < F_IN)
                v = *reinterpret_cast<const float4*>(W + (size_t)gk * H_DIM + f4c * 4);
            *reinterpret_cast<float4*>(&ws[krow][f4c * 4]) = v;
        }
        __syncthreads();

        #pragma unroll
        for (int k = 0; k < BK; ++k) {
            float4 xa0 = *reinterpret_cast<const float4*>(&xs[k][trow * 8]);
            float4 xa1 = *reinterpret_cast<const float4*>(&xs[k][trow * 8 + 4]);
            float4 wb  = *reinterpret_cast<const float4*>(&ws[k][tc * 4]);
            float xr[8] = {xa0.x, xa0.y, xa0.z, xa0.w, xa1.x, xa1.y, xa1.z, xa1.w};
            float wr[4] = {wb.x, wb.y, wb.z, wb.w};
            #pragma unroll
            for (int i = 0; i < 8; ++i)
                #pragma unroll
                for (int j = 0; j < 4; ++j)
                    acc[i][j] = fmaf(xr[i], wr[j], acc[i][j]);
        }
        __syncthreads();
    }

    float4 bias = *reinterpret_cast<const float4*>(b + tc * 4);
    #pragma unroll
    for (int i = 0; i < 8; ++i) {
        int gr = r0 + trow * 8 + i;
        if (gr < N_NODES) {
            float4 v;
            v.x = acc[i][0] + bias.x;
            v.y = acc[i][1] + bias.y;
            v.z = acc[i][2] + bias.z;
            v.w = acc[i][3] + bias.w;
            size_t idx = (size_t)gr * H_DIM + tc * 4;
            *reinterpret_cast<float4*>(x0 + idx) = v;
            *reinterpret_cast<float4*>(z  + idx) = v;
        }
    }
}

// ---------------- CSR build ----------------
__global__ void hist_kernel(const int* __restrict__ src, int* __restrict__ counts)
{
    int e = blockIdx.x * 256 + threadIdx.x;
    if (e < N_EDGES) atomicAdd(&counts[src[e]], 1);
}

__global__ __launch_bounds__(256) void scan_kernel(
    const int* __restrict__ counts, int* __restrict__ off, int* __restrict__ cursor)
{
    __shared__ int sums[256];
    __shared__ int bases[257];
    int tid = threadIdx.x;
    const int chunk = (N_NODES + 255) / 256;
    int s0 = tid * chunk;
    int s1 = s0 + chunk; if (s1 > N_NODES) s1 = N_NODES;
    int s = 0;
    for (int i = s0; i < s1; ++i) s += counts[i];
    sums[tid] = s;
    __syncthreads();
    if (tid == 0) {
        int r = 0;
        for (int i = 0; i < 256; ++i) { bases[i] = r; r += sums[i]; }
        bases[256] = r;
    }
    __syncthreads();
    int r = bases[tid];
    for (int i = s0; i < s1; ++i) {
        off[i] = r; cursor[i] = r; r += counts[i];
    }
    if (tid == 0) off[N_NODES] = bases[256];
}

__global__ void scatter_kernel(const int* __restrict__ src, const int* __restrict__ dst,
                               const float* __restrict__ w,
                               int* __restrict__ cursor, int* __restrict__ dsts,
                               float* __restrict__ wst)
{
    int e = blockIdx.x * 256 + threadIdx.x;
    if (e < N_EDGES) {
        int s = src[e];
        int p = atomicAdd(&cursor[s], 1);
        dsts[p] = dst[e];
        wst[p]  = w[e];
    }
}

// ---------------- Fused RK4 stage ----------------
__global__ __launch_bounds__(256) void stage_kernel(
    const int* __restrict__ off, const int* __restrict__ dsts,
    const float* __restrict__ wst,
    const float* __restrict__ zs, const float* zbase,
    const float* __restrict__ x0, const float* __restrict__ alpha,
    float* __restrict__ acc, float* out,
    int stage, float cnext)
{
    int node = blockIdx.x * 16 + (threadIdx.x >> 4);
    if (node >= N_NODES) return;
    int c = (threadIdx.x & 15) << 2;

    int jb = off[node], je = off[node + 1];
    float4 az = make_float4(0.f, 0.f, 0.f, 0.f);
    for (int j = jb; j < je; ++j) {
        int   d = dsts[j];
        float w = wst[j];
        const float4 zv = *reinterpret_cast<const float4*>(zs + (size_t)d * H_DIM + c);
        az.x = fmaf(w, zv.x, az.x);
        az.y = fmaf(w, zv.y, az.y);
        az.z = fmaf(w, zv.z, az.z);
        az.w = fmaf(w, zv.w, az.w);
    }

    size_t idx = (size_t)node * H_DIM + c;
    const float4 zsv = *reinterpret_cast<const float4*>(zs + idx);
    const float4 x0v = *reinterpret_cast<const float4*>(x0 + idx);
    float a = 0.5f / (1.f + __expf(-alpha[node]));

    float4 k;
    k.x = fmaf(a, az.x - zsv.x, x0v.x);
    k.y = fmaf(a, az.y - zsv.y, x0v.y);
    k.z = fmaf(a, az.z - zsv.z, x0v.z);
    k.w = fmaf(a, az.w - zsv.w, x0v.w);

    float4 zb = *reinterpret_cast<const float4*>(zbase + idx);
    float4 o;
    if (stage == 3) {
        float4 av = *reinterpret_cast<const float4*>(acc + idx);
        o.x = fmaf(cnext, av.x + k.x, zb.x);
        o.y = fmaf(cnext, av.y + k.y, zb.y);
        o.z = fmaf(cnext, av.z + k.z, zb.z);
        o.w = fmaf(cnext, av.w + k.w, zb.w);
    } else {
        if (stage == 0) {
            *reinterpret_cast<float4*>(acc + idx) = k;
        } else {
            float4 av = *reinterpret_cast<const float4*>(acc + idx);
            av.x = fmaf(2.f, k.x, av.x);
            av.y = fmaf(2.f, k.y, av.y);
            av.z = fmaf(2.f, k.z, av.z);
            av.w = fmaf(2.f, k.w, av.w);
            *reinterpret_cast<float4*>(acc + idx) = av;
        }
        o.x = fmaf(cnext, k.x, zb.x);
        o.y = fmaf(cnext, k.y, zb.y);
        o.z = fmaf(cnext, k.z, zb.z);
        o.w = fmaf(cnext, k.w, zb.w);
    }
    *reinterpret_cast<float4*>(out + idx) = o;
}

// ---------------- Decoder: out = relu(z) @ m2_w + m2_b ----------------
__global__ __launch_bounds__(256) void decoder_kernel(
    const float* __restrict__ z, const float* __restrict__ W2,
    const float* __restrict__ b2, float* __restrict__ out)
{
    int node = blockIdx.x * 4 + (threadIdx.x >> 6);
    int cc   = threadIdx.x & 63;
    if (node >= N_NODES || cc >= C_OUT) return;
    const float* zr = z + (size_t)node * H_DIM;
    float acc = 0.f;
    for (int k = 0; k < H_DIM; ++k) {
        float zv = zr[k];
        zv = zv > 0.f ? zv : 0.f;
        acc = fmaf(zv, W2[k * C_OUT + cc], acc);
    }
    out[node * C_OUT + cc] = acc + b2[cc];
}

extern "C" void kernel_launch(void* const* d_in, const int* in_sizes, int n_in,
                              void* d_out, int out_size, void* d_ws, size_t ws_size,
                              hipStream_t stream)
{
    const float* x     = (const float*)d_in[0];
    const float* ew    = (const float*)d_in[1];
    const float* m1w   = (const float*)d_in[2];
    const float* m1b   = (const float*)d_in[3];
    const float* alpha = (const float*)d_in[4];
    const float* m2w   = (const float*)d_in[5];
    const float* m2b   = (const float*)d_in[6];
    const int*   esrc  = (const int*)d_in[7];
    const int*   edst  = (const int*)d_in[8];
    float* out = (float*)d_out;

    char* ws = (char*)d_ws;
    size_t o = 0;
    auto alloc = [&](size_t bytes) -> void* {
        void* p = ws + o;
        o = (o + bytes + 255) & ~(size_t)255;
        return p;
    };
    float* x0     = (float*)alloc((size_t)N_NODES * H_DIM * 4);
    float* z      = (float*)alloc((size_t)N_NODES * H_DIM * 4);
    float* ztA    = (float*)alloc((size_t)N_NODES * H_DIM * 4);
    float* ztB    = (float*)alloc((size_t)N_NODES * H_DIM * 4);
    float* acc    = (float*)alloc((size_t)N_NODES * H_DIM * 4);
    int*   counts = (int*)alloc((size_t)N_NODES * 4);
    int*   off    = (int*)alloc((size_t)(N_NODES + 1) * 4);
    int*   cursor = (int*)alloc((size_t)N_NODES * 4);
    int*   dsts   = (int*)alloc((size_t)N_EDGES * 4);
    float* wst    = (float*)alloc((size_t)N_EDGES * 4);

    hipMemsetAsync(counts, 0, (size_t)N_NODES * 4, stream);
    hist_kernel<<<(N_EDGES + 255) / 256, 256, 0, stream>>>(esrc, counts);
    scan_kernel<<<1, 256, 0, stream>>>(counts, off, cursor);
    scatter_kernel<<<(N_EDGES + 255) / 256, 256, 0, stream>>>(esrc, edst, ew, cursor, dsts, wst);

    encoder_kernel<<<(N_NODES + BM - 1) / BM, 256, 0, stream>>>(x, m1w, m1b, x0, z);

    const float dt = 1.0f / STEPS;
    int sgrid = (N_NODES + 15) / 16;
    for (int step = 0; step < STEPS; ++step) {
        stage_kernel<<<sgrid, 256, 0, stream>>>(off, dsts, wst, z,   z, x0, alpha, acc, ztA, 0, 0.5f * dt);
        stage_kernel<<<sgrid, 256, 0, stream>>>(off, dsts, wst, ztA, z, x0, alpha, acc, ztB, 1, 0.5f * dt);
        stage_kernel<<<sgrid, 256, 0, stream>>>(off, dsts, wst, ztB, z, x0, alpha, acc, ztA, 2, dt);
        stage_kernel<<<sgrid, 256, 0, stream>>>(off, dsts, wst, ztA, z, x0, alpha, acc, z,   3, dt / 6.0f);
    }

    decoder_kernel<<<(N_NODES + 3) / 4, 256, 0, stream>>>(z, m2w, m2b, out);
}

// Round 3
// 647.957 us; speedup vs baseline: 1.5650x; 1.3089x over previous
//
#include <hip/hip_runtime.h>

#define N_NODES 50000
#define N_EDGES 600000
#define F_IN    500
#define H_DIM   64
#define C_OUT   40
#define STEPS   4
#define NB_SCAN ((N_NODES + 255) / 256)   // 196

// ---------------- Encoder: h = x @ m1_w + m1_b ; z = x0 = h ----------------
#define BM 128
#define BK 32
#define XS_STRIDE (BM + 4)
#define WS_STRIDE (H_DIM + 4)

__global__ __launch_bounds__(256) void encoder_kernel(
    const float* __restrict__ x, const float* __restrict__ W,
    const float* __restrict__ b, float* __restrict__ x0, float* __restrict__ z)
{
    __shared__ __align__(16) float xs[BK][XS_STRIDE];
    __shared__ __align__(16) float ws[BK][WS_STRIDE];

    int t    = threadIdx.x;
    int r0   = blockIdx.x * BM;
    int trow = t >> 4;
    int tc   = t & 15;

    float acc[8][4];
    #pragma unroll
    for (int i = 0; i < 8; ++i)
        #pragma unroll
        for (int j = 0; j < 4; ++j) acc[i][j] = 0.f;

    for (int k0 = 0; k0 < 512; k0 += BK) {
        #pragma unroll
        for (int s = 0; s < 4; ++s) {
            int idx = s * 256 + t;
            int row = idx >> 3;
            int f4  = idx & 7;
            int gr  = r0 + row; if (gr >= N_NODES) gr = N_NODES - 1;
            int gk  = k0 + f4 * 4;
            float4 v = make_float4(0.f, 0.f, 0.f, 0.f);
            if (gk + 3 < F_IN)
                v = *reinterpret_cast<const float4*>(x + (size_t)gr * F_IN + gk);
            xs[f4 * 4 + 0][row] = v.x;
            xs[f4 * 4 + 1][row] = v.y;
            xs[f4 * 4 + 2][row] = v.z;
            xs[f4 * 4 + 3][row] = v.w;
        }
        #pragma unroll
        for (int s = 0; s < 2; ++s) {
            int idx  = s * 256 + t;
            int krow = idx >> 4;
            int f4c  = idx & 15;
            int gk   = k0 + krow;
            float4 v = make_float4(0.f, 0.f, 0.f, 0.f);
            if (gk < F_IN)
                v = *reinterpret_cast<const float4*>(W + (size_t)gk * H_DIM + f4c * 4);
            *reinterpret_cast<float4*>(&ws[krow][f4c * 4]) = v;
        }
        __syncthreads();

        #pragma unroll
        for (int k = 0; k < BK; ++k) {
            float4 xa0 = *reinterpret_cast<const float4*>(&xs[k][trow * 8]);
            float4 xa1 = *reinterpret_cast<const float4*>(&xs[k][trow * 8 + 4]);
            float4 wb  = *reinterpret_cast<const float4*>(&ws[k][tc * 4]);
            float xr[8] = {xa0.x, xa0.y, xa0.z, xa0.w, xa1.x, xa1.y, xa1.z, xa1.w};
            float wr[4] = {wb.x, wb.y, wb.z, wb.w};
            #pragma unroll
            for (int i = 0; i < 8; ++i)
                #pragma unroll
                for (int j = 0; j < 4; ++j)
                    acc[i][j] = fmaf(xr[i], wr[j], acc[i][j]);
        }
        __syncthreads();
    }

    float4 bias = *reinterpret_cast<const float4*>(b + tc * 4);
    #pragma unroll
    for (int i = 0; i < 8; ++i) {
        int gr = r0 + trow * 8 + i;
        if (gr < N_NODES) {
            float4 v;
            v.x = acc[i][0] + bias.x;
            v.y = acc[i][1] + bias.y;
            v.z = acc[i][2] + bias.z;
            v.w = acc[i][3] + bias.w;
            size_t idx = (size_t)gr * H_DIM + tc * 4;
            *reinterpret_cast<float4*>(x0 + idx) = v;
            *reinterpret_cast<float4*>(z  + idx) = v;
        }
    }
}

// ---------------- CSR build ----------------
__global__ void hist_kernel(const int* __restrict__ src, int* __restrict__ counts)
{
    int e = blockIdx.x * 256 + threadIdx.x;
    if (e < N_EDGES) atomicAdd(&counts[src[e]], 1);
}

// Phase A: per-chunk sums (196 blocks x 256)
__global__ __launch_bounds__(256) void scanA_kernel(
    const int* __restrict__ counts, int* __restrict__ blockSums)
{
    __shared__ int red[256];
    int i = blockIdx.x * 256 + threadIdx.x;
    red[threadIdx.x] = (i < N_NODES) ? counts[i] : 0;
    __syncthreads();
    #pragma unroll
    for (int s = 128; s > 0; s >>= 1) {
        if (threadIdx.x < s) red[threadIdx.x] += red[threadIdx.x + s];
        __syncthreads();
    }
    if (threadIdx.x == 0) blockSums[blockIdx.x] = red[0];
}

// Phase B: scan of the 196 chunk sums (1 block)
__global__ __launch_bounds__(256) void scanB_kernel(
    const int* __restrict__ blockSums, int* __restrict__ blockBases)
{
    __shared__ int s[256];
    int tid = threadIdx.x;
    int v = (tid < NB_SCAN) ? blockSums[tid] : 0;
    s[tid] = v;
    __syncthreads();
    #pragma unroll
    for (int d = 1; d < 256; d <<= 1) {
        int t = (tid >= d) ? s[tid - d] : 0;
        __syncthreads();
        s[tid] += t;
        __syncthreads();
    }
    if (tid < NB_SCAN) blockBases[tid] = s[tid] - v;   // exclusive base
}

// Phase C: per-chunk exclusive scan + base -> off, cursor
__global__ __launch_bounds__(256) void scanC_kernel(
    const int* __restrict__ counts, const int* __restrict__ blockBases,
    int* __restrict__ off, int* __restrict__ cursor)
{
    __shared__ int s[256];
    int tid = threadIdx.x;
    int i = blockIdx.x * 256 + tid;
    int v = (i < N_NODES) ? counts[i] : 0;
    s[tid] = v;
    __syncthreads();
    #pragma unroll
    for (int d = 1; d < 256; d <<= 1) {
        int t = (tid >= d) ? s[tid - d] : 0;
        __syncthreads();
        s[tid] += t;
        __syncthreads();
    }
    if (i < N_NODES) {
        int excl = blockBases[blockIdx.x] + s[tid] - v;
        off[i] = excl;
        cursor[i] = excl;
        if (i == N_NODES - 1) off[N_NODES] = excl + v;
    }
}

__global__ void scatter_kernel(const int* __restrict__ src, const int* __restrict__ dst,
                               const float* __restrict__ w,
                               int* __restrict__ cursor, int2* __restrict__ epack)
{
    int e = blockIdx.x * 256 + threadIdx.x;
    if (e < N_EDGES) {
        int s = src[e];
        int p = atomicAdd(&cursor[s], 1);
        epack[p] = make_int2(dst[e], __float_as_int(w[e]));
    }
}

// ---------------- Fused RK4 stage ----------------
// 16 threads per node; edge loop unrolled x4 with independent accumulators
// so each 16-lane group keeps 4 gathers in flight.
__global__ __launch_bounds__(256) void stage_kernel(
    const int* __restrict__ off, const int2* __restrict__ epack,
    const float* __restrict__ zs, const float* zbase,
    const float* __restrict__ x0, const float* __restrict__ alpha,
    float* __restrict__ acc, float* out,
    int stage, float cnext)
{
    int node = blockIdx.x * 16 + (threadIdx.x >> 4);
    if (node >= N_NODES) return;
    int c = (threadIdx.x & 15) << 2;

    int jb = off[node], je = off[node + 1];
    float4 az0 = make_float4(0.f, 0.f, 0.f, 0.f);
    float4 az1 = make_float4(0.f, 0.f, 0.f, 0.f);
    float4 az2 = make_float4(0.f, 0.f, 0.f, 0.f);
    float4 az3 = make_float4(0.f, 0.f, 0.f, 0.f);
    int j = jb;
    for (; j + 3 < je; j += 4) {
        int2 e0 = epack[j];
        int2 e1 = epack[j + 1];
        int2 e2 = epack[j + 2];
        int2 e3 = epack[j + 3];
        const float4 z0 = *reinterpret_cast<const float4*>(zs + (size_t)e0.x * H_DIM + c);
        const float4 z1 = *reinterpret_cast<const float4*>(zs + (size_t)e1.x * H_DIM + c);
        const float4 z2 = *reinterpret_cast<const float4*>(zs + (size_t)e2.x * H_DIM + c);
        const float4 z3 = *reinterpret_cast<const float4*>(zs + (size_t)e3.x * H_DIM + c);
        float w0 = __int_as_float(e0.y), w1 = __int_as_float(e1.y);
        float w2 = __int_as_float(e2.y), w3 = __int_as_float(e3.y);
        az0.x = fmaf(w0, z0.x, az0.x); az0.y = fmaf(w0, z0.y, az0.y);
        az0.z = fmaf(w0, z0.z, az0.z); az0.w = fmaf(w0, z0.w, az0.w);
        az1.x = fmaf(w1, z1.x, az1.x); az1.y = fmaf(w1, z1.y, az1.y);
        az1.z = fmaf(w1, z1.z, az1.z); az1.w = fmaf(w1, z1.w, az1.w);
        az2.x = fmaf(w2, z2.x, az2.x); az2.y = fmaf(w2, z2.y, az2.y);
        az2.z = fmaf(w2, z2.z, az2.z); az2.w = fmaf(w2, z2.w, az2.w);
        az3.x = fmaf(w3, z3.x, az3.x); az3.y = fmaf(w3, z3.y, az3.y);
        az3.z = fmaf(w3, z3.z, az3.z); az3.w = fmaf(w3, z3.w, az3.w);
    }
    for (; j < je; ++j) {
        int2 e0 = epack[j];
        const float4 z0 = *reinterpret_cast<const float4*>(zs + (size_t)e0.x * H_DIM + c);
        float w0 = __int_as_float(e0.y);
        az0.x = fmaf(w0, z0.x, az0.x); az0.y = fmaf(w0, z0.y, az0.y);
        az0.z = fmaf(w0, z0.z, az0.z); az0.w = fmaf(w0, z0.w, az0.w);
    }
    float4 az;
    az.x = (az0.x + az1.x) + (az2.x + az3.x);
    az.y = (az0.y + az1.y) + (az2.y + az3.y);
    az.z = (az0.z + az1.z) + (az2.z + az3.z);
    az.w = (az0.w + az1.w) + (az2.w + az3.w);

    size_t idx = (size_t)node * H_DIM + c;
    const float4 zsv = *reinterpret_cast<const float4*>(zs + idx);
    const float4 x0v = *reinterpret_cast<const float4*>(x0 + idx);
    float a = 0.5f / (1.f + __expf(-alpha[node]));

    float4 k;
    k.x = fmaf(a, az.x - zsv.x, x0v.x);
    k.y = fmaf(a, az.y - zsv.y, x0v.y);
    k.z = fmaf(a, az.z - zsv.z, x0v.z);
    k.w = fmaf(a, az.w - zsv.w, x0v.w);

    float4 zb = *reinterpret_cast<const float4*>(zbase + idx);
    float4 o;
    if (stage == 3) {
        float4 av = *reinterpret_cast<const float4*>(acc + idx);
        o.x = fmaf(cnext, av.x + k.x, zb.x);
        o.y = fmaf(cnext, av.y + k.y, zb.y);
        o.z = fmaf(cnext, av.z + k.z, zb.z);
        o.w = fmaf(cnext, av.w + k.w, zb.w);
    } else {
        if (stage == 0) {
            *reinterpret_cast<float4*>(acc + idx) = k;
        } else {
            float4 av = *reinterpret_cast<const float4*>(acc + idx);
            av.x = fmaf(2.f, k.x, av.x);
            av.y = fmaf(2.f, k.y, av.y);
            av.z = fmaf(2.f, k.z, av.z);
            av.w = fmaf(2.f, k.w, av.w);
            *reinterpret_cast<float4*>(acc + idx) = av;
        }
        o.x = fmaf(cnext, k.x, zb.x);
        o.y = fmaf(cnext, k.y, zb.y);
        o.z = fmaf(cnext, k.z, zb.z);
        o.w = fmaf(cnext, k.w, zb.w);
    }
    *reinterpret_cast<float4*>(out + idx) = o;
}

// ---------------- Decoder: out = relu(z) @ m2_w + m2_b ----------------
__global__ __launch_bounds__(256) void decoder_kernel(
    const float* __restrict__ z, const float* __restrict__ W2,
    const float* __restrict__ b2, float* __restrict__ out)
{
    int node = blockIdx.x * 4 + (threadIdx.x >> 6);
    int cc   = threadIdx.x & 63;
    if (node >= N_NODES || cc >= C_OUT) return;
    const float* zr = z + (size_t)node * H_DIM;
    float acc = 0.f;
    for (int k = 0; k < H_DIM; ++k) {
        float zv = zr[k];
        zv = zv > 0.f ? zv : 0.f;
        acc = fmaf(zv, W2[k * C_OUT + cc], acc);
    }
    out[node * C_OUT + cc] = acc + b2[cc];
}

extern "C" void kernel_launch(void* const* d_in, const int* in_sizes, int n_in,
                              void* d_out, int out_size, void* d_ws, size_t ws_size,
                              hipStream_t stream)
{
    const float* x     = (const float*)d_in[0];
    const float* ew    = (const float*)d_in[1];
    const float* m1w   = (const float*)d_in[2];
    const float* m1b   = (const float*)d_in[3];
    const float* alpha = (const float*)d_in[4];
    const float* m2w   = (const float*)d_in[5];
    const float* m2b   = (const float*)d_in[6];
    const int*   esrc  = (const int*)d_in[7];
    const int*   edst  = (const int*)d_in[8];
    float* out = (float*)d_out;

    char* ws = (char*)d_ws;
    size_t o = 0;
    auto alloc = [&](size_t bytes) -> void* {
        void* p = ws + o;
        o = (o + bytes + 255) & ~(size_t)255;
        return p;
    };
    float* x0      = (float*)alloc((size_t)N_NODES * H_DIM * 4);
    float* z       = (float*)alloc((size_t)N_NODES * H_DIM * 4);
    float* ztA     = (float*)alloc((size_t)N_NODES * H_DIM * 4);
    float* ztB     = (float*)alloc((size_t)N_NODES * H_DIM * 4);
    float* acc     = (float*)alloc((size_t)N_NODES * H_DIM * 4);
    int*   counts  = (int*)alloc((size_t)N_NODES * 4);
    int*   off     = (int*)alloc((size_t)(N_NODES + 1) * 4);
    int*   cursor  = (int*)alloc((size_t)N_NODES * 4);
    int*   bsums   = (int*)alloc((size_t)NB_SCAN * 4);
    int*   bbases  = (int*)alloc((size_t)NB_SCAN * 4);
    int2*  epack   = (int2*)alloc((size_t)N_EDGES * 8);

    hipMemsetAsync(counts, 0, (size_t)N_NODES * 4, stream);
    hist_kernel<<<(N_EDGES + 255) / 256, 256, 0, stream>>>(esrc, counts);
    scanA_kernel<<<NB_SCAN, 256, 0, stream>>>(counts, bsums);
    scanB_kernel<<<1, 256, 0, stream>>>(bsums, bbases);
    scanC_kernel<<<NB_SCAN, 256, 0, stream>>>(counts, bbases, off, cursor);
    scatter_kernel<<<(N_EDGES + 255) / 256, 256, 0, stream>>>(esrc, edst, ew, cursor, epack);

    encoder_kernel<<<(N_NODES + BM - 1) / BM, 256, 0, stream>>>(x, m1w, m1b, x0, z);

    const float dt = 1.0f / STEPS;
    int sgrid = (N_NODES + 15) / 16;
    for (int step = 0; step < STEPS; ++step) {
        stage_kernel<<<sgrid, 256, 0, stream>>>(off, epack, z,   z, x0, alpha, acc, ztA, 0, 0.5f * dt);
        stage_kernel<<<sgrid, 256, 0, stream>>>(off, epack, ztA, z, x0, alpha, acc, ztB, 1, 0.5f * dt);
        stage_kernel<<<sgrid, 256, 0, stream>>>(off, epack, ztB, z, x0, alpha, acc, ztA, 2, dt);
        stage_kernel<<<sgrid, 256, 0, stream>>>(off, epack, ztA, z, x0, alpha, acc, z,   3, dt / 6.0f);
    }

    decoder_kernel<<<(N_NODES + 3) / 4, 256, 0, stream>>>(z, m2w, m2b, out);
}